// Round 1
// baseline (2723.266 us; speedup 1.0000x reference)
//
#include <hip/hip_runtime.h>
#include <cstddef>

// NLM: h=7/255, template 7x7 (TH=3), search 21x21 (SH=10), reflect padding.
// Tile 32x32 per 256-thread block. LDS: x halo 13 each side (58x58),
// d region 38x38, hsum 38x32.

constexpr int TS   = 32;           // tile size
constexpr int XH   = 13;           // x halo = SH(10) + TH(3)
constexpr int XDIM = TS + 2 * XH;  // 58
constexpr int XSTR = XDIM + 2;     // 60 (pad for bank behavior)
constexpr int DH   = 3;            // template radius
constexpr int DDIM = TS + 2 * DH;  // 38
constexpr int DSTR = 40;
constexpr int HSTR = TS + 1;       // 33
constexpr int SW   = 21;           // search window

__device__ __forceinline__ int refl(int i, int n) {
    // np.pad 'reflect' (no edge repeat); single reflection is sufficient
    // for the |overshoot| <= 13+10 range we use (n = 1024).
    i = (i < 0) ? -i : i;
    return (i >= n) ? (2 * n - 2 - i) : i;
}

__global__ __launch_bounds__(256)
void nlm_kernel(const float* __restrict__ img_all, float* __restrict__ out,
                int H, int W) {
    __shared__ float xs[XDIM * XSTR];
    __shared__ float ds[DDIM * DSTR];
    __shared__ float hs[DDIM * HSTR];
    __shared__ int   dmy[DDIM];
    __shared__ int   dmx[DDIM];

    const int tid = threadIdx.x;
    const int gx0 = blockIdx.x * TS;
    const int gy0 = blockIdx.y * TS;
    const int b   = blockIdx.z;
    const float* img = img_all + (size_t)b * H * W;

    // Load x tile + halo with reflect indexing, clipped to [0,1].
    for (int e = tid; e < XDIM * XDIM; e += 256) {
        int i = e / XDIM;
        int j = e - i * XDIM;
        int gy = refl(gy0 - XH + i, H);
        int gx = refl(gx0 - XH + j, W);
        float v = img[(size_t)gy * W + gx];
        v = fminf(fmaxf(v, 0.0f), 1.0f);
        xs[i * XSTR + j] = v;
    }
    // Reflect maps for the d-array box-filter padding:
    // d_lds[a][c] corresponds to global (gy0+a-3, gx0+c-3); the box filter
    // reflects the d *array* at image edges, so we evaluate d at the
    // reflected position. dmy/dmx give that position's xs row/col index.
    if (tid < DDIM) {
        dmy[tid] = refl(gy0 + tid - DH, H) - gy0 + XH;
        dmx[tid] = refl(gx0 + tid - DH, W) - gx0 + XH;
    }
    __syncthreads();

    const int px  = tid & 31;        // pixel column in tile
    const int py  = (tid >> 5) * 4;  // first of 4 pixel rows for this thread

    float wsum[4] = {0.f, 0.f, 0.f, 0.f};
    float vsum[4] = {0.f, 0.f, 0.f, 0.f};

    // w = exp(-mean49(d)/H2) = exp2(K * sum49(d)),
    // K = -log2(e) / (49 * (7/255)^2) = -(65025/2401)*log2(e)
    const float K = -(65025.0f / 2401.0f) * 1.4426950408889634f;

    for (int oy = 0; oy < SW; ++oy) {
        const int dy = oy - 10;
        for (int ox = 0; ox < SW; ++ox) {
            const int dx = ox - 10;

            // Stage A: d over 38x38 (with reflect maps)
            for (int e = tid; e < DDIM * DDIM; e += 256) {
                int a = e / DDIM;
                int c = e - a * DDIM;
                int my = dmy[a];
                int mx = dmx[c];
                float v = xs[my * XSTR + mx] - xs[(my + dy) * XSTR + (mx + dx)];
                ds[a * DSTR + c] = v * v;
            }
            __syncthreads();

            // Stage B: horizontal 7-sums -> hs[38][32]
            for (int e = tid; e < DDIM * TS; e += 256) {
                int a = e >> 5;
                int c = e & 31;
                const float* row = &ds[a * DSTR + c];
                float s = row[0] + row[1] + row[2] + row[3] + row[4] + row[5] + row[6];
                hs[a * HSTR + c] = s;
            }
            __syncthreads();

            // Stage C: vertical sliding 7-sums for 4 pixels, weight + accum
            float r[10];
#pragma unroll
            for (int t = 0; t < 10; ++t) r[t] = hs[(py + t) * HSTR + px];
            float s0 = ((r[0] + r[1]) + (r[2] + r[3])) + ((r[4] + r[5]) + r[6]);
            float s1 = s0 - r[0] + r[7];
            float s2 = s1 - r[1] + r[8];
            float s3 = s2 - r[2] + r[9];
            float sums[4] = {s0, s1, s2, s3};
#pragma unroll
            for (int k = 0; k < 4; ++k) {
                float w  = __builtin_amdgcn_exp2f(sums[k] * K);
                float sv = xs[(py + k + XH + dy) * XSTR + (px + XH + dx)];
                wsum[k] += w;
                vsum[k] = fmaf(w, sv, vsum[k]);
            }
            // Next stage A (ds writes) is fenced from this iter's B reads by
            // the barrier after A; hs writes of next B are fenced from this
            // C's reads by that same barrier. No third barrier needed.
        }
    }

#pragma unroll
    for (int k = 0; k < 4; ++k) {
        float inv = __builtin_amdgcn_rcpf(wsum[k]);
        float o = vsum[k] * inv;
        o = fminf(fmaxf(o, 0.0f), 1.0f);
        out[((size_t)b * H + (gy0 + py + k)) * W + (gx0 + px)] = o;
    }
}

extern "C" void kernel_launch(void* const* d_in, const int* in_sizes, int n_in,
                              void* d_out, int out_size, void* d_ws, size_t ws_size,
                              hipStream_t stream) {
    const float* x = (const float*)d_in[0];
    float* out = (float*)d_out;
    const int H = 1024, W = 1024;
    const int B = in_sizes[0] / (H * W);
    dim3 grid(W / TS, H / TS, B);
    nlm_kernel<<<grid, dim3(256), 0, stream>>>(x, out, H, W);
}